// Round 15
// baseline (1206.315 us; speedup 1.0000x reference)
//
#include <hip/hip_runtime.h>
#include <stdint.h>

// x: (8,128,16,16) f32 ; codebook: (4,4096,32) f32 ; temperature: (4,1,1,1)
// row = (n*4+m)*256 + hw, 8192 rows, K=4096, D=32
// outputs (flat f32): sample[33554432] code[8192] one_hot[33554432] logit[33554432]
//
// ROUND 14 (resubmit after infra failure) = Round-13 kernel + ONE change:
// the block's zero-fill stores are interleaved into the gumbel j-loop
// (2 float4/thread/iter) instead of a naked burst at kernel end. Fill has
// no dependencies -> no new barriers.

__device__ __forceinline__ uint32_t rotl32(uint32_t x, uint32_t r){
  return (x << r) | (x >> (32u - r));
}

// JAX threefry2x32, key (0,42), partitionable scheme: bits = o0^o1 of
// threefry((0,42),(0,e)); u = bitcast((bits>>9)|0x3F800000)-1, clip.
// gumbel = -log(-log(u)) via v_log_f32. Threefry bits VALIDATED bit-exact
// (R2,4,6,7,8,10); fast-log path VALIDATED (R11,R12,R13, no argmax flips).
__device__ __forceinline__ float gumbel_from_e(uint32_t e){
  uint32_t x0 = 0u, x1 = e;
  const uint32_t ks0 = 0u, ks1 = 42u, ks2 = 0x1BD11BF0u;
  x0 += ks0; x1 += ks1;
#define TFR4(a,b,c,d2) \
  x0 += x1; x1 = rotl32(x1,(a)); x1 ^= x0; \
  x0 += x1; x1 = rotl32(x1,(b)); x1 ^= x0; \
  x0 += x1; x1 = rotl32(x1,(c)); x1 ^= x0; \
  x0 += x1; x1 = rotl32(x1,(d2)); x1 ^= x0;
  TFR4(13,15,26,6)  x0 += ks1; x1 += ks2 + 1u;
  TFR4(17,29,16,24) x0 += ks2; x1 += ks0 + 2u;
  TFR4(13,15,26,6)  x0 += ks0; x1 += ks1 + 3u;
  TFR4(17,29,16,24) x0 += ks1; x1 += ks2 + 4u;
  TFR4(13,15,26,6)  x0 += ks2; x1 += ks0 + 5u;
#undef TFR4
  uint32_t bits = x0 ^ x1;
  float u = __uint_as_float((bits >> 9) | 0x3F800000u) - 1.0f;
  u = fminf(fmaxf(u, 1.1920929e-07f), __uint_as_float(0x3F7FFFFEu));
  const float LN2 = 0.69314718055994531f;
  float v = -LN2 * __log2f(u);        // -ln(u)
  return -LN2 * __log2f(v);           // -ln(-ln(u))
}

// Kernel 1: grid 4096 = m(4) x rowtile(64) x ktile(16); block 512 thr,
// 32 rows x 256 k. Stride-33 codebook LDS, c2/x2 from LDS post-barrier,
// LDS two-stage argmax, zero-fill interleaved into the gumbel loop
// (no trailing barrier anywhere after stores — R7 lesson).
__global__ __launch_bounds__(512, 8) void k_logits(
    const float* __restrict__ x, const float* __restrict__ cb,
    const float* __restrict__ temp, float* __restrict__ logit_out,
    float* __restrict__ sample, float* __restrict__ onehot){
  __shared__ float xl[32][36];     // 32 rows x 32 d, pad to 36
  __shared__ float cl[8448];       // 256 k x 32 d, stride 33 (33792 B)
  __shared__ float c2l[256];
  __shared__ float x2l[32];

  const int tid = threadIdx.x;
  const int b = blockIdx.x;
  const int kt = b & 15;           // k-tile 0..15
  const int rt = (b >> 4) & 63;    // row-tile 0..63 (within m)
  const int m  = b >> 10;          // 0..3
  const int n  = rt >> 3;
  const int hw0 = (rt & 7) << 5;
  const int k0 = kt << 8;
  const int rowbase = ((n << 2) + m) * 256 + hw0;

  // ---- stage x tile (32 rows x 32 d) ----
  const float* xm = x + ((n * 128 + m * 32) * 256 + hw0);
  #pragma unroll
  for (int i = 0; i < 2; ++i){
    int idx = tid + (i << 9);
    int d = idx >> 5, r = idx & 31;
    xl[r][d] = xm[(d << 8) + r];
  }
  // ---- stage codebook tile (256 k x 32 d) as float4, stride 33 ----
  const float4* cb4 = (const float4*)(cb + (m * 131072 + k0 * 32));
  #pragma unroll
  for (int i = 0; i < 4; ++i){
    int f = tid + (i << 9);
    float4 v = cb4[f];
    int kk = f >> 3, dq = f & 7;
    *(float4*)&cl[kk * 33 + (dq << 2)] = v;
  }
  __syncthreads();

  // ---- squared norms ----
  if (tid < 256){
    float s = 0.f;
    #pragma unroll
    for (int d = 0; d < 32; ++d){ float c = cl[tid*33 + d]; s = fmaf(c, c, s); }
    c2l[tid] = s;
  }
  if (tid < 32){
    float s = 0.f;
    #pragma unroll
    for (int d = 0; d < 32; ++d){ float v = xl[tid][d]; s = fmaf(v, v, s); }
    x2l[tid] = s;
  }
  __syncthreads();

  // ---- GEMM: each thread 4 rows x 4 ks ----
  const int kg = tid & 63;         // k-group 0..63, ks = kg + 64*j
  const int rg = tid >> 6;         // row-group 0..7 (uniform per wave)
  float acc[4][4];
  #pragma unroll
  for (int i = 0; i < 4; ++i)
    #pragma unroll
    for (int j = 0; j < 4; ++j) acc[i][j] = 0.f;

  #pragma unroll
  for (int dblk = 0; dblk < 8; ++dblk){
    float4 xa[4];
    #pragma unroll
    for (int i = 0; i < 4; ++i)
      xa[i] = *(const float4*)&xl[(rg << 2) + i][dblk << 2];
    #pragma unroll
    for (int j = 0; j < 4; ++j){
      float4 cv = *(const float4*)&cl[(kg + (j << 6)) * 33 + (dblk << 2)];
      #pragma unroll
      for (int i = 0; i < 4; ++i){
        acc[i][j] = fmaf(xa[i].x, cv.x, acc[i][j]);
        acc[i][j] = fmaf(xa[i].y, cv.y, acc[i][j]);
        acc[i][j] = fmaf(xa[i].z, cv.z, acc[i][j]);
        acc[i][j] = fmaf(xa[i].w, cv.w, acc[i][j]);
      }
    }
  }

  // ---- logits + gumbel + per-thread argmax, with the block's zero-fill
  // interleaved (2 float4 stores per j-iter, paced by ~16 gumbels of VALU) ----
  const float tcl = fmaxf(temp[m], 1e-6f);
  const float4 z4 = make_float4(0.f, 0.f, 0.f, 0.f);
  float bl[4], bg[4]; int bli[4], bgi[4];
  #pragma unroll
  for (int i = 0; i < 4; ++i){ bl[i] = -INFINITY; bg[i] = -INFINITY; bli[i] = 0; bgi[i] = 0; }

  #pragma unroll
  for (int j = 0; j < 4; ++j){
    const int kk = kg + (j << 6);
    const int k_g = k0 + kk;
    const float c2 = c2l[kk];
    #pragma unroll
    for (int i = 0; i < 4; ++i){
      const int r = (rg << 2) + i;
      const int row_g = rowbase + r;
      float dist = x2l[r] + c2 - 2.0f * acc[i][j];
      float l = (-dist) * 0.015625f * tcl;          // (-dist/64)*t, /64 exact
      logit_out[((size_t)row_g << 12) + k_g] = l;
      float lg = l + gumbel_from_e(((uint32_t)row_g << 12) + (uint32_t)k_g);
      if (l  > bl[i]) { bl[i] = l;  bli[i] = k_g; }
      if (lg > bg[i]) { bg[i] = lg; bgi[i] = k_g; }
    }
    // interleaved zero-fill slice j (same addresses as the old tail loop)
    {
      int s = tid + (j << 9);           // 2048 float4 slots: 32 rows x 64
      int r2 = s >> 6, w4 = s & 63;
      size_t f4 = (((size_t)(rowbase + r2)) << 10) + (k0 >> 2) + w4;
      ((float4*)onehot)[f4] = z4;
      if (!(kt == 0 && w4 < 16))        // keep sample[row][0:64] = partials
        ((float4*)sample)[f4] = z4;
    }
  }

  // ---- block reduction over 64 k-groups (reuse cl as scratch: 8320 <= 8448) ----
  __syncthreads();                 // all cl reads done
  float* red = cl;                 // 4 arrays of 32*65 floats (pad 65)
  #pragma unroll
  for (int i = 0; i < 4; ++i){
    int r = (rg << 2) + i;
    red[        r * 65 + kg] = bl[i];
    red[2080 +  r * 65 + kg] = __int_as_float(bli[i]);
    red[4160 +  r * 65 + kg] = bg[i];
    red[6240 +  r * 65 + kg] = __int_as_float(bgi[i]);
  }
  __syncthreads();
  if (tid < 64){
    const int r = tid & 31;
    const bool doG = (tid >= 32);
    const int off_v = doG ? 4160 : 0;
    const int off_i = doG ? 6240 : 2080;
    float bv = -INFINITY; int bi = 0;
    for (int g2 = 0; g2 < 64; ++g2){
      float v = red[off_v + r * 65 + g2];
      int  ix = __float_as_int(red[off_i + r * 65 + g2]);
      if (v > bv || (v == bv && ix < bi)){ bv = v; bi = ix; }
    }
    const int row_g = rowbase + r;
    float* part = sample + ((size_t)row_g << 12);
    part[(doG ? 32 : 0)  + kt] = bv;
    part[(doG ? 48 : 16) + kt] = __int_as_float(bi);
  }
}

// Kernel 2: one wave per row (2048 blocks x 256 = 4 rows/block). Shuffle-reduce
// the 16 partials, zero sample[row][0:64], scatter the two 1.0s + code.
__global__ __launch_bounds__(256) void k_finalize(
    float* __restrict__ sample, float* __restrict__ code_out,
    float* __restrict__ onehot){
  const int tid = threadIdx.x;
  const int row = (blockIdx.x << 2) + (tid >> 6);
  const int lane = tid & 63;
  float* srow = sample + ((size_t)row << 12);
  float* orow = onehot + ((size_t)row << 12);

  // lanes 0-15 reduce L (logit argmax), lanes 16-31 reduce G (logit+gumbel)
  const int g = (lane >> 4) & 1;
  const int l16 = lane & 15;
  float v; int ix;
  if (lane < 32){
    v  = srow[g * 32 + l16];
    ix = __float_as_int(srow[g * 32 + 16 + l16]);
  } else { v = -INFINITY; ix = 0x7fffffff; }
  #pragma unroll
  for (int off = 1; off < 16; off <<= 1){
    float ov = __shfl_xor(v, off, 16);
    int   oi = __shfl_xor(ix, off, 16);
    if (ov > v || (ov == v && oi < ix)){ v = ov; ix = oi; }
  }
  const int codei = __shfl(ix, 0, 64);   // L winner
  const int hard  = __shfl(ix, 16, 64);  // G winner

  // zero sample[row][0:64]; owner lane embeds the 1.0 if hard < 64 (no race)
  if (lane < 16){
    float4 vs = make_float4(0.f, 0.f, 0.f, 0.f);
    if ((hard >> 2) == lane) ((float*)&vs)[hard & 3] = 1.0f;
    ((float4*)srow)[lane] = vs;
  } else if (lane == 16){
    if (hard >= 64) srow[hard] = 1.0f;   // region already zeroed by K1
  } else if (lane == 17){
    orow[codei] = 1.0f;                  // one_hot(argmax(logit)); zeroed by K1
  } else if (lane == 18){
    code_out[row] = (float)codei;
  }
}

extern "C" void kernel_launch(void* const* d_in, const int* in_sizes, int n_in,
                              void* d_out, int out_size, void* d_ws, size_t ws_size,
                              hipStream_t stream) {
  const float* x    = (const float*)d_in[0];
  const float* cb   = (const float*)d_in[1];
  const float* temp = (const float*)d_in[2];
  float* out    = (float*)d_out;
  float* sample = out;                       // 33554432
  float* code   = out + 33554432;            // 8192
  float* onehot = code + 8192;               // 33554432
  float* logit  = onehot + 33554432;         // 33554432

  hipLaunchKernelGGL(k_logits, dim3(4096), dim3(512), 0, stream,
                     x, cb, temp, logit, sample, onehot);
  hipLaunchKernelGGL(k_finalize, dim3(2048), dim3(256), 0, stream,
                     sample, code, onehot);
}

// Round 16
// 184.560 us; speedup vs baseline: 6.5362x; 6.5362x over previous
//
#include <hip/hip_runtime.h>
#include <stdint.h>

// x: (8,128,16,16) f32 ; codebook: (4,4096,32) f32 ; temperature: (4,1,1,1)
// row = (n*4+m)*256 + hw, 8192 rows, K=4096, D=32
// outputs (flat f32): sample[33554432] code[8192] one_hot[33554432] logit[33554432]
//
// ROUND 16 = 3-phase: (1) hipMemsetAsync zeroes sample+code+onehot at the
// device's native fill rate (~7 TB/s, measured on this buffer via the
// harness's own fills); (2) K1 = R13 kernel WITHOUT the fill tail (logit +
// argmax partials only); (3) K2 scatter unchanged.
// R15 lesson: interleaved fill under a VGPR cap spilled acc to scratch
// (VGPR=32, 4.3GB hbm traffic) — never add live state in the hot loop.

__device__ __forceinline__ uint32_t rotl32(uint32_t x, uint32_t r){
  return (x << r) | (x >> (32u - r));
}

// JAX threefry2x32, key (0,42), partitionable scheme: bits = o0^o1 of
// threefry((0,42),(0,e)); u = bitcast((bits>>9)|0x3F800000)-1, clip.
// gumbel = -log(-log(u)) via v_log_f32. Threefry bits VALIDATED bit-exact
// (R2,4,6,7,8,10); fast-log path VALIDATED (R11,R12,R13,R15).
__device__ __forceinline__ float gumbel_from_e(uint32_t e){
  uint32_t x0 = 0u, x1 = e;
  const uint32_t ks0 = 0u, ks1 = 42u, ks2 = 0x1BD11BF0u;
  x0 += ks0; x1 += ks1;
#define TFR4(a,b,c,d2) \
  x0 += x1; x1 = rotl32(x1,(a)); x1 ^= x0; \
  x0 += x1; x1 = rotl32(x1,(b)); x1 ^= x0; \
  x0 += x1; x1 = rotl32(x1,(c)); x1 ^= x0; \
  x0 += x1; x1 = rotl32(x1,(d2)); x1 ^= x0;
  TFR4(13,15,26,6)  x0 += ks1; x1 += ks2 + 1u;
  TFR4(17,29,16,24) x0 += ks2; x1 += ks0 + 2u;
  TFR4(13,15,26,6)  x0 += ks0; x1 += ks1 + 3u;
  TFR4(17,29,16,24) x0 += ks1; x1 += ks2 + 4u;
  TFR4(13,15,26,6)  x0 += ks2; x1 += ks0 + 5u;
#undef TFR4
  uint32_t bits = x0 ^ x1;
  float u = __uint_as_float((bits >> 9) | 0x3F800000u) - 1.0f;
  u = fminf(fmaxf(u, 1.1920929e-07f), __uint_as_float(0x3F7FFFFEu));
  const float LN2 = 0.69314718055994531f;
  float v = -LN2 * __log2f(u);        // -ln(u)
  return -LN2 * __log2f(v);           // -ln(-ln(u))
}

// Kernel 1: grid 4096 = m(4) x rowtile(64) x ktile(16); block 512 thr,
// 32 rows x 256 k. Stride-33 codebook LDS, c2/x2 from LDS post-barrier,
// LDS two-stage argmax, partials into sample[row][0:64] (post-memset).
// NO zero-fill here (memset owns it).
__global__ __launch_bounds__(512, 8) void k_logits(
    const float* __restrict__ x, const float* __restrict__ cb,
    const float* __restrict__ temp, float* __restrict__ logit_out,
    float* __restrict__ sample){
  __shared__ float xl[32][36];     // 32 rows x 32 d, pad to 36
  __shared__ float cl[8448];       // 256 k x 32 d, stride 33 (33792 B)
  __shared__ float c2l[256];
  __shared__ float x2l[32];

  const int tid = threadIdx.x;
  const int b = blockIdx.x;
  const int kt = b & 15;           // k-tile 0..15
  const int rt = (b >> 4) & 63;    // row-tile 0..63 (within m)
  const int m  = b >> 10;          // 0..3
  const int n  = rt >> 3;
  const int hw0 = (rt & 7) << 5;
  const int k0 = kt << 8;
  const int rowbase = ((n << 2) + m) * 256 + hw0;

  // ---- stage x tile (32 rows x 32 d) ----
  const float* xm = x + ((n * 128 + m * 32) * 256 + hw0);
  #pragma unroll
  for (int i = 0; i < 2; ++i){
    int idx = tid + (i << 9);
    int d = idx >> 5, r = idx & 31;
    xl[r][d] = xm[(d << 8) + r];
  }
  // ---- stage codebook tile (256 k x 32 d) as float4, stride 33 ----
  const float4* cb4 = (const float4*)(cb + (m * 131072 + k0 * 32));
  #pragma unroll
  for (int i = 0; i < 4; ++i){
    int f = tid + (i << 9);
    float4 v = cb4[f];
    int kk = f >> 3, dq = f & 7;
    *(float4*)&cl[kk * 33 + (dq << 2)] = v;
  }
  __syncthreads();

  // ---- squared norms ----
  if (tid < 256){
    float s = 0.f;
    #pragma unroll
    for (int d = 0; d < 32; ++d){ float c = cl[tid*33 + d]; s = fmaf(c, c, s); }
    c2l[tid] = s;
  }
  if (tid < 32){
    float s = 0.f;
    #pragma unroll
    for (int d = 0; d < 32; ++d){ float v = xl[tid][d]; s = fmaf(v, v, s); }
    x2l[tid] = s;
  }
  __syncthreads();

  // ---- GEMM: each thread 4 rows x 4 ks ----
  const int kg = tid & 63;         // k-group 0..63, ks = kg + 64*j
  const int rg = tid >> 6;         // row-group 0..7 (uniform per wave)
  float acc[4][4];
  #pragma unroll
  for (int i = 0; i < 4; ++i)
    #pragma unroll
    for (int j = 0; j < 4; ++j) acc[i][j] = 0.f;

  #pragma unroll
  for (int dblk = 0; dblk < 8; ++dblk){
    float4 xa[4];
    #pragma unroll
    for (int i = 0; i < 4; ++i)
      xa[i] = *(const float4*)&xl[(rg << 2) + i][dblk << 2];
    #pragma unroll
    for (int j = 0; j < 4; ++j){
      float4 cv = *(const float4*)&cl[(kg + (j << 6)) * 33 + (dblk << 2)];
      #pragma unroll
      for (int i = 0; i < 4; ++i){
        acc[i][j] = fmaf(xa[i].x, cv.x, acc[i][j]);
        acc[i][j] = fmaf(xa[i].y, cv.y, acc[i][j]);
        acc[i][j] = fmaf(xa[i].z, cv.z, acc[i][j]);
        acc[i][j] = fmaf(xa[i].w, cv.w, acc[i][j]);
      }
    }
  }

  // ---- logits + gumbel + per-thread argmax (k ascending -> first-occurrence) ----
  const float tcl = fmaxf(temp[m], 1e-6f);
  float bl[4], bg[4]; int bli[4], bgi[4];
  #pragma unroll
  for (int i = 0; i < 4; ++i){ bl[i] = -INFINITY; bg[i] = -INFINITY; bli[i] = 0; bgi[i] = 0; }

  #pragma unroll
  for (int j = 0; j < 4; ++j){
    const int kk = kg + (j << 6);
    const int k_g = k0 + kk;
    const float c2 = c2l[kk];
    #pragma unroll
    for (int i = 0; i < 4; ++i){
      const int r = (rg << 2) + i;
      const int row_g = rowbase + r;
      float dist = x2l[r] + c2 - 2.0f * acc[i][j];
      float l = (-dist) * 0.015625f * tcl;          // (-dist/64)*t, /64 exact
      logit_out[((size_t)row_g << 12) + k_g] = l;
      float lg = l + gumbel_from_e(((uint32_t)row_g << 12) + (uint32_t)k_g);
      if (l  > bl[i]) { bl[i] = l;  bli[i] = k_g; }
      if (lg > bg[i]) { bg[i] = lg; bgi[i] = k_g; }
    }
  }

  // ---- block reduction over 64 k-groups (reuse cl as scratch: 8320 <= 8448) ----
  __syncthreads();                 // all cl reads done
  float* red = cl;                 // 4 arrays of 32*65 floats (pad 65)
  #pragma unroll
  for (int i = 0; i < 4; ++i){
    int r = (rg << 2) + i;
    red[        r * 65 + kg] = bl[i];
    red[2080 +  r * 65 + kg] = __int_as_float(bli[i]);
    red[4160 +  r * 65 + kg] = bg[i];
    red[6240 +  r * 65 + kg] = __int_as_float(bgi[i]);
  }
  __syncthreads();
  if (tid < 64){
    const int r = tid & 31;
    const bool doG = (tid >= 32);
    const int off_v = doG ? 4160 : 0;
    const int off_i = doG ? 6240 : 2080;
    float bv = -INFINITY; int bi = 0;
    for (int g2 = 0; g2 < 64; ++g2){
      float v = red[off_v + r * 65 + g2];
      int  ix = __float_as_int(red[off_i + r * 65 + g2]);
      if (v > bv || (v == bv && ix < bi)){ bv = v; bi = ix; }
    }
    const int row_g = rowbase + r;
    float* part = sample + ((size_t)row_g << 12);
    part[(doG ? 32 : 0)  + kt] = bv;
    part[(doG ? 48 : 16) + kt] = __int_as_float(bi);
  }
}

// Kernel 2: one wave per row (2048 blocks x 256 = 4 rows/block). Shuffle-reduce
// the 16 partials, zero sample[row][0:64], scatter the two 1.0s + code.
__global__ __launch_bounds__(256) void k_finalize(
    float* __restrict__ sample, float* __restrict__ code_out,
    float* __restrict__ onehot){
  const int tid = threadIdx.x;
  const int row = (blockIdx.x << 2) + (tid >> 6);
  const int lane = tid & 63;
  float* srow = sample + ((size_t)row << 12);
  float* orow = onehot + ((size_t)row << 12);

  // lanes 0-15 reduce L (logit argmax), lanes 16-31 reduce G (logit+gumbel)
  const int g = (lane >> 4) & 1;
  const int l16 = lane & 15;
  float v; int ix;
  if (lane < 32){
    v  = srow[g * 32 + l16];
    ix = __float_as_int(srow[g * 32 + 16 + l16]);
  } else { v = -INFINITY; ix = 0x7fffffff; }
  #pragma unroll
  for (int off = 1; off < 16; off <<= 1){
    float ov = __shfl_xor(v, off, 16);
    int   oi = __shfl_xor(ix, off, 16);
    if (ov > v || (ov == v && oi < ix)){ v = ov; ix = oi; }
  }
  const int codei = __shfl(ix, 0, 64);   // L winner
  const int hard  = __shfl(ix, 16, 64);  // G winner

  // zero sample[row][0:64]; owner lane embeds the 1.0 if hard < 64 (no race)
  if (lane < 16){
    float4 vs = make_float4(0.f, 0.f, 0.f, 0.f);
    if ((hard >> 2) == lane) ((float*)&vs)[hard & 3] = 1.0f;
    ((float4*)srow)[lane] = vs;
  } else if (lane == 16){
    if (hard >= 64) srow[hard] = 1.0f;   // region zeroed by the memset
  } else if (lane == 17){
    orow[codei] = 1.0f;                  // one_hot(argmax(logit)); zeroed by memset
  } else if (lane == 18){
    code_out[row] = (float)codei;
  }
}

extern "C" void kernel_launch(void* const* d_in, const int* in_sizes, int n_in,
                              void* d_out, int out_size, void* d_ws, size_t ws_size,
                              hipStream_t stream) {
  const float* x    = (const float*)d_in[0];
  const float* cb   = (const float*)d_in[1];
  const float* temp = (const float*)d_in[2];
  float* out    = (float*)d_out;
  float* sample = out;                       // 33554432
  float* code   = out + 33554432;            // 8192
  float* onehot = code + 8192;               // 33554432
  float* logit  = onehot + 33554432;         // 33554432

  // Phase 1: zero sample+code+onehot in one native fill (~7 TB/s).
  // code is fully rewritten by k_finalize, so covering it is free and
  // lets this be a single contiguous memset of 268.5 MB.
  hipMemsetAsync(out, 0, (size_t)(33554432 + 8192 + 33554432) * sizeof(float),
                 stream);

  // Phase 2: logits + gumbel + argmax partials.
  hipLaunchKernelGGL(k_logits, dim3(4096), dim3(512), 0, stream,
                     x, cb, temp, logit, sample);

  // Phase 3: reduce partials, scatter 1.0s + code.
  hipLaunchKernelGGL(k_finalize, dim3(2048), dim3(256), 0, stream,
                     sample, code, onehot);
}

// Round 17
// 138.041 us; speedup vs baseline: 8.7388x; 1.3370x over previous
//
#include <hip/hip_runtime.h>
#include <stdint.h>

// x: (8,128,16,16) f32 ; codebook: (4,4096,32) f32 ; temperature: (4,1,1,1)
// row = (n*4+m)*256 + hw, 8192 rows, K=4096, D=32
// outputs (flat f32): sample[33554432] code[8192] one_hot[33554432] logit[33554432]
//
// ROUND 17 = R13 structure with the fp32 VALU GEMM replaced by bf16x3
// split-precision MFMA (mfma_f32_16x16x32_bf16): inter = Ah*Bh + Ah*Bl + Al*Bh,
// error ~2^-16 -> logit err ~1e-5, far below observed top-2 gaps (~2e-3).
// Removes ~50 ds_read_b128/thread + 128 VALU FMA from the critical path.
// Fill tail, LDS argmax, fast-log, K2 unchanged from R13 (144.5us anchor).

typedef short bf16x8 __attribute__((ext_vector_type(8)));
typedef float f32x4  __attribute__((ext_vector_type(4)));

__device__ __forceinline__ uint32_t rotl32(uint32_t x, uint32_t r){
  return (x << r) | (x >> (32u - r));
}

// JAX threefry2x32, key (0,42), partitionable scheme. Bits VALIDATED bit-exact
// (R2,4,6,...); fast-log path VALIDATED (R11,R12,R13).
__device__ __forceinline__ float gumbel_from_e(uint32_t e){
  uint32_t x0 = 0u, x1 = e;
  const uint32_t ks0 = 0u, ks1 = 42u, ks2 = 0x1BD11BF0u;
  x0 += ks0; x1 += ks1;
#define TFR4(a,b,c,d2) \
  x0 += x1; x1 = rotl32(x1,(a)); x1 ^= x0; \
  x0 += x1; x1 = rotl32(x1,(b)); x1 ^= x0; \
  x0 += x1; x1 = rotl32(x1,(c)); x1 ^= x0; \
  x0 += x1; x1 = rotl32(x1,(d2)); x1 ^= x0;
  TFR4(13,15,26,6)  x0 += ks1; x1 += ks2 + 1u;
  TFR4(17,29,16,24) x0 += ks2; x1 += ks0 + 2u;
  TFR4(13,15,26,6)  x0 += ks0; x1 += ks1 + 3u;
  TFR4(17,29,16,24) x0 += ks1; x1 += ks2 + 4u;
  TFR4(13,15,26,6)  x0 += ks2; x1 += ks0 + 5u;
#undef TFR4
  uint32_t bits = x0 ^ x1;
  float u = __uint_as_float((bits >> 9) | 0x3F800000u) - 1.0f;
  u = fminf(fmaxf(u, 1.1920929e-07f), __uint_as_float(0x3F7FFFFEu));
  const float LN2 = 0.69314718055994531f;
  float v = -LN2 * __log2f(u);
  return -LN2 * __log2f(v);
}

// Truncating bf16 split: v ~= hi + lo, |v-(hi+lo)| <= 2^-16 |v|.
__device__ __forceinline__ void split_bf16(float v, unsigned short& hi, unsigned short& lo){
  uint32_t b = __float_as_uint(v);
  hi = (unsigned short)(b >> 16);
  float r = v - __uint_as_float(b & 0xFFFF0000u);   // exact residual
  lo = (unsigned short)(__float_as_uint(r) >> 16);
}

// Kernel 1: grid 4096 = m(4) x rowtile(64) x ktile(16); block 512 thr (8 waves),
// 32 rows x 256 k. bf16 hi/lo planes in LDS (row pad 40 elems = 80B, 16B-aligned
// fragment reads). Wave w: m-half = w>>2, n-group = w&3 -> 4 tiles of 16x16,
// K=32 in one MFMA x 3 passes. LDS two-stage argmax (slot order-independent,
// min-index tiebreak). Zero-fill tail, no trailing barrier (R7 lesson).
__global__ __launch_bounds__(512) void k_logits(
    const float* __restrict__ x, const float* __restrict__ cb,
    const float* __restrict__ temp, float* __restrict__ logit_out,
    float* __restrict__ sample, float* __restrict__ onehot){
  __shared__ __align__(16) unsigned short cbuf[20480]; // hi[0..10239], lo[10240..] : 256 x 40
  __shared__ __align__(16) unsigned short xbuf[2560];  // hi[0..1279],  lo[1280..]  : 32 x 40
  __shared__ float c2l[256];
  __shared__ float x2l[32];

  const int tid = threadIdx.x;
  const int b = blockIdx.x;
  const int kt = b & 15;
  const int rt = (b >> 4) & 63;
  const int m  = b >> 10;
  const int n  = rt >> 3;
  const int hw0 = (rt & 7) << 5;
  const int k0 = kt << 8;
  const int rowbase = ((n << 2) + m) * 256 + hw0;

  // ---- stage x tile (32 rows x 32 d) as bf16 hi/lo planes ----
  const float* xm = x + ((n * 128 + m * 32) * 256 + hw0);
  #pragma unroll
  for (int i = 0; i < 2; ++i){
    int idx = tid + (i << 9);
    int d = idx >> 5, r = idx & 31;
    float v = xm[(d << 8) + r];
    unsigned short h, l;
    split_bf16(v, h, l);
    xbuf[r * 40 + d] = h;
    xbuf[1280 + r * 40 + d] = l;
  }
  // ---- stage codebook tile (256 k x 32 d): bf16 hi/lo + shuffle-tree c2 ----
  const float4* cb4 = (const float4*)(cb + (m * 131072 + k0 * 32));
  #pragma unroll
  for (int i = 0; i < 4; ++i){
    int f = tid + (i << 9);
    float4 v = cb4[f];
    int kk = f >> 3, dq = f & 7;
    unsigned short h0,h1,h2,h3,l0,l1,l2,l3;
    split_bf16(v.x, h0, l0); split_bf16(v.y, h1, l1);
    split_bf16(v.z, h2, l2); split_bf16(v.w, h3, l3);
    uint2 hw_, lw_;
    hw_.x = (uint32_t)h0 | ((uint32_t)h1 << 16);
    hw_.y = (uint32_t)h2 | ((uint32_t)h3 << 16);
    lw_.x = (uint32_t)l0 | ((uint32_t)l1 << 16);
    lw_.y = (uint32_t)l2 | ((uint32_t)l3 << 16);
    *(uint2*)&cbuf[kk * 40 + (dq << 2)] = hw_;
    *(uint2*)&cbuf[10240 + kk * 40 + (dq << 2)] = lw_;
    // c2 = sum c^2 (fp32, from original values) via 8-lane shuffle tree (R8-validated)
    float p = fmaf(v.x, v.x, fmaf(v.y, v.y, fmaf(v.z, v.z, v.w * v.w)));
    p += __shfl_xor(p, 1);
    p += __shfl_xor(p, 2);
    p += __shfl_xor(p, 4);
    if (dq == 0) c2l[kk] = p;
  }
  __syncthreads();   // planes + c2l complete

  // ---- x2 from recombined planes (consistent with MFMA's x-tilde) ----
  if (tid < 32){
    float s = 0.f;
    #pragma unroll
    for (int d = 0; d < 32; ++d){
      float vh = __uint_as_float(((uint32_t)xbuf[tid * 40 + d]) << 16);
      float vl = __uint_as_float(((uint32_t)xbuf[1280 + tid * 40 + d]) << 16);
      float v = vh + vl;
      s = fmaf(v, v, s);
    }
    x2l[tid] = s;
  }
  __syncthreads();   // x2l visible

  const int lane = tid & 63;
  const int w    = tid >> 6;
  const int mh   = w >> 2;          // m-half 0/1
  const int ng   = w & 3;           // n-group 0..3
  const int l15  = lane & 15;
  const int kgrp = lane >> 4;       // 0..3

  // A fragments (reused across 4 n-tiles): row = mh*16 + l15, k = kgrp*8..+7
  bf16x8 Ah = *(const bf16x8*)&xbuf[(mh * 16 + l15) * 40 + (kgrp << 3)];
  bf16x8 Al = *(const bf16x8*)&xbuf[1280 + (mh * 16 + l15) * 40 + (kgrp << 3)];

  // D rows owned by this lane: r_blk(j) = mh*16 + kgrp*4 + j
  float x2r[4];
  #pragma unroll
  for (int j = 0; j < 4; ++j) x2r[j] = x2l[mh * 16 + (kgrp << 2) + j];

  const float tcl = fmaxf(temp[m], 1e-6f);
  float bl[4], bg[4]; int bli[4], bgi[4];
  #pragma unroll
  for (int j = 0; j < 4; ++j){ bl[j] = -INFINITY; bg[j] = -INFINITY; bli[j] = 0; bgi[j] = 0; }

  #pragma unroll
  for (int t = 0; t < 4; ++t){
    const int nt = (ng << 2) + t;           // n-tile 0..15
    const int k_blk = (nt << 4) + l15;      // this lane's codebook index (column)
    bf16x8 Bh = *(const bf16x8*)&cbuf[k_blk * 40 + (kgrp << 3)];
    bf16x8 Bl = *(const bf16x8*)&cbuf[10240 + k_blk * 40 + (kgrp << 3)];
    f32x4 acc = {0.f, 0.f, 0.f, 0.f};
    acc = __builtin_amdgcn_mfma_f32_16x16x32_bf16(Ah, Bh, acc, 0, 0, 0);
    acc = __builtin_amdgcn_mfma_f32_16x16x32_bf16(Ah, Bl, acc, 0, 0, 0);
    acc = __builtin_amdgcn_mfma_f32_16x16x32_bf16(Al, Bh, acc, 0, 0, 0);

    const float c2 = c2l[k_blk];
    const int k_g = k0 + k_blk;
    #pragma unroll
    for (int j = 0; j < 4; ++j){
      const int r_blk = mh * 16 + (kgrp << 2) + j;   // D: row=(lane>>4)*4+reg (m89/m91)
      const int row_g = rowbase + r_blk;
      float dist = x2r[j] + c2 - 2.0f * acc[j];
      float lgt = (-dist) * 0.015625f * tcl;
      logit_out[((size_t)row_g << 12) + k_g] = lgt;
      float lg = lgt + gumbel_from_e(((uint32_t)row_g << 12) + (uint32_t)k_g);
      if (lgt > bl[j]) { bl[j] = lgt; bli[j] = k_g; }   // t ascending -> k ascending
      if (lg  > bg[j]) { bg[j] = lg;  bgi[j] = k_g; }
    }
  }

  // ---- two-stage LDS argmax reduction (scratch overlays cbuf; 33280B <= 40960B)
  __syncthreads();   // all MFMA reads of cbuf done
  float* red = (float*)cbuf;   // 4 arrays of 32x65
  #pragma unroll
  for (int j = 0; j < 4; ++j){
    int row = mh * 16 + (kgrp << 2) + j;
    int slot = (ng << 4) + l15;             // 64 slots/row; order-independent (min-idx tiebreak)
    red[        row * 65 + slot] = bl[j];
    red[2080 +  row * 65 + slot] = __int_as_float(bli[j]);
    red[4160 +  row * 65 + slot] = bg[j];
    red[6240 +  row * 65 + slot] = __int_as_float(bgi[j]);
  }
  __syncthreads();
  if (tid < 64){
    const int r = tid & 31;
    const bool doG = (tid >= 32);
    const int off_v = doG ? 4160 : 0;
    const int off_i = doG ? 6240 : 2080;
    float bv = -INFINITY; int bi = 0;
    for (int g2 = 0; g2 < 64; ++g2){
      float v = red[off_v + r * 65 + g2];
      int  ix = __float_as_int(red[off_i + r * 65 + g2]);
      if (v > bv || (v == bv && ix < bi)){ bv = v; bi = ix; }
    }
    float* part = sample + ((size_t)(rowbase + r) << 12);
    part[(doG ? 32 : 0)  + kt] = bv;
    part[(doG ? 48 : 16) + kt] = __int_as_float(bi);
  }

  // ---- zero-fill this block's disjoint slice LAST (fire-and-forget) ----
  const float4 z4 = make_float4(0.f, 0.f, 0.f, 0.f);
  #pragma unroll
  for (int i2 = 0; i2 < 4; ++i2){
    int s = tid + (i2 << 9);
    int r = s >> 6, w4 = s & 63;
    size_t f4 = (((size_t)(rowbase + r)) << 10) + (k0 >> 2) + w4;
    ((float4*)onehot)[f4] = z4;
    if (!(kt == 0 && w4 < 16))
      ((float4*)sample)[f4] = z4;
  }
}

// Kernel 2: one wave per row. Shuffle-reduce the 16 partials, zero
// sample[row][0:64], scatter the two 1.0s + code. (Unchanged, validated.)
__global__ __launch_bounds__(256) void k_finalize(
    float* __restrict__ sample, float* __restrict__ code_out,
    float* __restrict__ onehot){
  const int tid = threadIdx.x;
  const int row = (blockIdx.x << 2) + (tid >> 6);
  const int lane = tid & 63;
  float* srow = sample + ((size_t)row << 12);
  float* orow = onehot + ((size_t)row << 12);

  const int g = (lane >> 4) & 1;
  const int l16 = lane & 15;
  float v; int ix;
  if (lane < 32){
    v  = srow[g * 32 + l16];
    ix = __float_as_int(srow[g * 32 + 16 + l16]);
  } else { v = -INFINITY; ix = 0x7fffffff; }
  #pragma unroll
  for (int off = 1; off < 16; off <<= 1){
    float ov = __shfl_xor(v, off, 16);
    int   oi = __shfl_xor(ix, off, 16);
    if (ov > v || (ov == v && oi < ix)){ v = ov; ix = oi; }
  }
  const int codei = __shfl(ix, 0, 64);
  const int hard  = __shfl(ix, 16, 64);

  if (lane < 16){
    float4 vs = make_float4(0.f, 0.f, 0.f, 0.f);
    if ((hard >> 2) == lane) ((float*)&vs)[hard & 3] = 1.0f;
    ((float4*)srow)[lane] = vs;
  } else if (lane == 16){
    if (hard >= 64) srow[hard] = 1.0f;
  } else if (lane == 17){
    orow[codei] = 1.0f;
  } else if (lane == 18){
    code_out[row] = (float)codei;
  }
}

extern "C" void kernel_launch(void* const* d_in, const int* in_sizes, int n_in,
                              void* d_out, int out_size, void* d_ws, size_t ws_size,
                              hipStream_t stream) {
  const float* x    = (const float*)d_in[0];
  const float* cb   = (const float*)d_in[1];
  const float* temp = (const float*)d_in[2];
  float* out    = (float*)d_out;
  float* sample = out;                       // 33554432
  float* code   = out + 33554432;            // 8192
  float* onehot = code + 8192;               // 33554432
  float* logit  = onehot + 33554432;         // 33554432

  hipLaunchKernelGGL(k_logits, dim3(4096), dim3(512), 0, stream,
                     x, cb, temp, logit, sample, onehot);
  hipLaunchKernelGGL(k_finalize, dim3(2048), dim3(256), 0, stream,
                     sample, code, onehot);
}

// Round 18
// 125.875 us; speedup vs baseline: 9.5834x; 1.0967x over previous
//
#include <hip/hip_runtime.h>
#include <stdint.h>

// x: (8,128,16,16) f32 ; codebook: (4,4096,32) f32 ; temperature: (4,1,1,1)
// row = (n*4+m)*256 + hw, 8192 rows, K=4096, D=32
// outputs (flat f32): sample[33554432] code[8192] one_hot[33554432] logit[33554432]
//
// ROUND 18 = R17 (bf16x3 MFMA GEMM, 138us) + ONE change: argmax partials move
// from sample[row][0:64] (16-block RMW line-bouncing) to a compact d_ws buffer
// ws[row*64 + kt*4 + {Lv,Li,Gv,Gi}] (one 16B chunk/block/row). sample fill is
// now uniform; K2 is pure scatter (no zeroing). Template fallback to the
// validated in-sample scheme if ws_size < 2MB.

typedef short bf16x8 __attribute__((ext_vector_type(8)));
typedef float f32x4  __attribute__((ext_vector_type(4)));

__device__ __forceinline__ uint32_t rotl32(uint32_t x, uint32_t r){
  return (x << r) | (x >> (32u - r));
}

// JAX threefry2x32, key (0,42), partitionable scheme. Bits VALIDATED bit-exact
// (R2,4,6..); fast-log path VALIDATED (R11,R12,R13,R17).
__device__ __forceinline__ float gumbel_from_e(uint32_t e){
  uint32_t x0 = 0u, x1 = e;
  const uint32_t ks0 = 0u, ks1 = 42u, ks2 = 0x1BD11BF0u;
  x0 += ks0; x1 += ks1;
#define TFR4(a,b,c,d2) \
  x0 += x1; x1 = rotl32(x1,(a)); x1 ^= x0; \
  x0 += x1; x1 = rotl32(x1,(b)); x1 ^= x0; \
  x0 += x1; x1 = rotl32(x1,(c)); x1 ^= x0; \
  x0 += x1; x1 = rotl32(x1,(d2)); x1 ^= x0;
  TFR4(13,15,26,6)  x0 += ks1; x1 += ks2 + 1u;
  TFR4(17,29,16,24) x0 += ks2; x1 += ks0 + 2u;
  TFR4(13,15,26,6)  x0 += ks0; x1 += ks1 + 3u;
  TFR4(17,29,16,24) x0 += ks1; x1 += ks2 + 4u;
  TFR4(13,15,26,6)  x0 += ks2; x1 += ks0 + 5u;
#undef TFR4
  uint32_t bits = x0 ^ x1;
  float u = __uint_as_float((bits >> 9) | 0x3F800000u) - 1.0f;
  u = fminf(fmaxf(u, 1.1920929e-07f), __uint_as_float(0x3F7FFFFEu));
  const float LN2 = 0.69314718055994531f;
  float v = -LN2 * __log2f(u);
  return -LN2 * __log2f(v);
}

// Truncating bf16 split: v ~= hi + lo, |v-(hi+lo)| <= 2^-16 |v|.
__device__ __forceinline__ void split_bf16(float v, unsigned short& hi, unsigned short& lo){
  uint32_t b = __float_as_uint(v);
  hi = (unsigned short)(b >> 16);
  float r = v - __uint_as_float(b & 0xFFFF0000u);
  lo = (unsigned short)(__float_as_uint(r) >> 16);
}

// Kernel 1: grid 4096 = m(4) x rowtile(64) x ktile(16); block 512 thr (8 waves),
// 32 rows x 256 k. bf16x3 MFMA GEMM (R17-validated layouts), LDS two-stage
// argmax, zero-fill tail with no trailing barrier (R7 lesson).
template<bool USE_WS>
__global__ __launch_bounds__(512) void k_logits(
    const float* __restrict__ x, const float* __restrict__ cb,
    const float* __restrict__ temp, float* __restrict__ logit_out,
    float* __restrict__ sample, float* __restrict__ onehot,
    float* __restrict__ part_ws){
  __shared__ __align__(16) unsigned short cbuf[20480]; // hi/lo planes: 256 x 40 each
  __shared__ __align__(16) unsigned short xbuf[2560];  // hi/lo planes: 32 x 40 each
  __shared__ float c2l[256];
  __shared__ float x2l[32];

  const int tid = threadIdx.x;
  const int b = blockIdx.x;
  const int kt = b & 15;
  const int rt = (b >> 4) & 63;
  const int m  = b >> 10;
  const int n  = rt >> 3;
  const int hw0 = (rt & 7) << 5;
  const int k0 = kt << 8;
  const int rowbase = ((n << 2) + m) * 256 + hw0;

  // ---- stage x tile (32 rows x 32 d) as bf16 hi/lo planes ----
  const float* xm = x + ((n * 128 + m * 32) * 256 + hw0);
  #pragma unroll
  for (int i = 0; i < 2; ++i){
    int idx = tid + (i << 9);
    int d = idx >> 5, r = idx & 31;
    float v = xm[(d << 8) + r];
    unsigned short h, l;
    split_bf16(v, h, l);
    xbuf[r * 40 + d] = h;
    xbuf[1280 + r * 40 + d] = l;
  }
  // ---- stage codebook tile: bf16 hi/lo + shuffle-tree c2 ----
  const float4* cb4 = (const float4*)(cb + (m * 131072 + k0 * 32));
  #pragma unroll
  for (int i = 0; i < 4; ++i){
    int f = tid + (i << 9);
    float4 v = cb4[f];
    int kk = f >> 3, dq = f & 7;
    unsigned short h0,h1,h2,h3,l0,l1,l2,l3;
    split_bf16(v.x, h0, l0); split_bf16(v.y, h1, l1);
    split_bf16(v.z, h2, l2); split_bf16(v.w, h3, l3);
    uint2 hw_, lw_;
    hw_.x = (uint32_t)h0 | ((uint32_t)h1 << 16);
    hw_.y = (uint32_t)h2 | ((uint32_t)h3 << 16);
    lw_.x = (uint32_t)l0 | ((uint32_t)l1 << 16);
    lw_.y = (uint32_t)l2 | ((uint32_t)l3 << 16);
    *(uint2*)&cbuf[kk * 40 + (dq << 2)] = hw_;
    *(uint2*)&cbuf[10240 + kk * 40 + (dq << 2)] = lw_;
    float p = fmaf(v.x, v.x, fmaf(v.y, v.y, fmaf(v.z, v.z, v.w * v.w)));
    p += __shfl_xor(p, 1);
    p += __shfl_xor(p, 2);
    p += __shfl_xor(p, 4);
    if (dq == 0) c2l[kk] = p;
  }
  __syncthreads();

  // ---- x2 from recombined planes (consistent with MFMA's x-tilde) ----
  if (tid < 32){
    float s = 0.f;
    #pragma unroll
    for (int d = 0; d < 32; ++d){
      float vh = __uint_as_float(((uint32_t)xbuf[tid * 40 + d]) << 16);
      float vl = __uint_as_float(((uint32_t)xbuf[1280 + tid * 40 + d]) << 16);
      float v = vh + vl;
      s = fmaf(v, v, s);
    }
    x2l[tid] = s;
  }
  __syncthreads();

  const int lane = tid & 63;
  const int w    = tid >> 6;
  const int mh   = w >> 2;
  const int ng   = w & 3;
  const int l15  = lane & 15;
  const int kgrp = lane >> 4;

  bf16x8 Ah = *(const bf16x8*)&xbuf[(mh * 16 + l15) * 40 + (kgrp << 3)];
  bf16x8 Al = *(const bf16x8*)&xbuf[1280 + (mh * 16 + l15) * 40 + (kgrp << 3)];

  float x2r[4];
  #pragma unroll
  for (int j = 0; j < 4; ++j) x2r[j] = x2l[mh * 16 + (kgrp << 2) + j];

  const float tcl = fmaxf(temp[m], 1e-6f);
  float bl[4], bg[4]; int bli[4], bgi[4];
  #pragma unroll
  for (int j = 0; j < 4; ++j){ bl[j] = -INFINITY; bg[j] = -INFINITY; bli[j] = 0; bgi[j] = 0; }

  #pragma unroll
  for (int t = 0; t < 4; ++t){
    const int nt = (ng << 2) + t;
    const int k_blk = (nt << 4) + l15;
    bf16x8 Bh = *(const bf16x8*)&cbuf[k_blk * 40 + (kgrp << 3)];
    bf16x8 Bl = *(const bf16x8*)&cbuf[10240 + k_blk * 40 + (kgrp << 3)];
    f32x4 acc = {0.f, 0.f, 0.f, 0.f};
    acc = __builtin_amdgcn_mfma_f32_16x16x32_bf16(Ah, Bh, acc, 0, 0, 0);
    acc = __builtin_amdgcn_mfma_f32_16x16x32_bf16(Ah, Bl, acc, 0, 0, 0);
    acc = __builtin_amdgcn_mfma_f32_16x16x32_bf16(Al, Bh, acc, 0, 0, 0);

    const float c2 = c2l[k_blk];
    const int k_g = k0 + k_blk;
    #pragma unroll
    for (int j = 0; j < 4; ++j){
      const int r_blk = mh * 16 + (kgrp << 2) + j;   // D: col=lane&15, row=(lane>>4)*4+reg
      const int row_g = rowbase + r_blk;
      float dist = x2r[j] + c2 - 2.0f * acc[j];
      float lgt = (-dist) * 0.015625f * tcl;
      logit_out[((size_t)row_g << 12) + k_g] = lgt;
      float lg = lgt + gumbel_from_e(((uint32_t)row_g << 12) + (uint32_t)k_g);
      if (lgt > bl[j]) { bl[j] = lgt; bli[j] = k_g; }
      if (lg  > bg[j]) { bg[j] = lg;  bgi[j] = k_g; }
    }
  }

  // ---- two-stage LDS argmax reduction (scratch overlays cbuf) ----
  __syncthreads();
  float* red = (float*)cbuf;
  #pragma unroll
  for (int j = 0; j < 4; ++j){
    int row = mh * 16 + (kgrp << 2) + j;
    int slot = (ng << 4) + l15;
    red[        row * 65 + slot] = bl[j];
    red[2080 +  row * 65 + slot] = __int_as_float(bli[j]);
    red[4160 +  row * 65 + slot] = bg[j];
    red[6240 +  row * 65 + slot] = __int_as_float(bgi[j]);
  }
  __syncthreads();
  if (tid < 64){
    const int r = tid & 31;
    const bool doG = (tid >= 32);
    const int off_v = doG ? 4160 : 0;
    const int off_i = doG ? 6240 : 2080;
    float bv = -INFINITY; int bi = 0;
    for (int g2 = 0; g2 < 64; ++g2){
      float v = red[off_v + r * 65 + g2];
      int  ix = __float_as_int(red[off_i + r * 65 + g2]);
      if (v > bv || (v == bv && ix < bi)){ bv = v; bi = ix; }
    }
    const int row_g = rowbase + r;
    if (USE_WS){
      // compact: ws[row*64 + kt*4 + {0,1}] = L, {2,3} = G (one 16B chunk/block/row)
      *(float2*)&part_ws[((size_t)row_g << 6) + (kt << 2) + (doG ? 2 : 0)]
          = make_float2(bv, __int_as_float(bi));
    } else {
      float* part = sample + ((size_t)row_g << 12);
      part[(doG ? 32 : 0)  + kt] = bv;
      part[(doG ? 48 : 16) + kt] = __int_as_float(bi);
    }
  }

  // ---- zero-fill this block's disjoint slice LAST (fire-and-forget) ----
  const float4 z4 = make_float4(0.f, 0.f, 0.f, 0.f);
  #pragma unroll
  for (int i2 = 0; i2 < 4; ++i2){
    int s = tid + (i2 << 9);
    int r = s >> 6, w4 = s & 63;
    size_t f4 = (((size_t)(rowbase + r)) << 10) + (k0 >> 2) + w4;
    ((float4*)onehot)[f4] = z4;
    if (USE_WS || !(kt == 0 && w4 < 16))
      ((float4*)sample)[f4] = z4;
  }
}

// Kernel 2: one wave per row (2048 blocks x 256). Reduce 16 partials, scatter.
template<bool USE_WS>
__global__ __launch_bounds__(256) void k_finalize(
    float* __restrict__ sample, float* __restrict__ code_out,
    float* __restrict__ onehot, const float* __restrict__ part_ws){
  const int tid = threadIdx.x;
  const int row = (blockIdx.x << 2) + (tid >> 6);
  const int lane = tid & 63;
  float* srow = sample + ((size_t)row << 12);
  float* orow = onehot + ((size_t)row << 12);

  const int g = (lane >> 4) & 1;
  const int l16 = lane & 15;
  float v; int ix;
  if (lane < 32){
    if (USE_WS){
      float2 p2 = *(const float2*)&part_ws[((size_t)row << 6) + (l16 << 2) + (g ? 2 : 0)];
      v = p2.x; ix = __float_as_int(p2.y);
    } else {
      v  = srow[g * 32 + l16];
      ix = __float_as_int(srow[g * 32 + 16 + l16]);
    }
  } else { v = -INFINITY; ix = 0x7fffffff; }
  #pragma unroll
  for (int off = 1; off < 16; off <<= 1){
    float ov = __shfl_xor(v, off, 16);
    int   oi = __shfl_xor(ix, off, 16);
    if (ov > v || (ov == v && oi < ix)){ v = ov; ix = oi; }
  }
  const int codei = __shfl(ix, 0, 64);   // L winner
  const int hard  = __shfl(ix, 16, 64);  // G winner

  if (USE_WS){
    // sample fully zeroed by K1 -> pure scatter
    if (lane == 0)      srow[hard]  = 1.0f;
    else if (lane == 1) orow[codei] = 1.0f;
    else if (lane == 2) code_out[row] = (float)codei;
  } else {
    if (lane < 16){
      float4 vs = make_float4(0.f, 0.f, 0.f, 0.f);
      if ((hard >> 2) == lane) ((float*)&vs)[hard & 3] = 1.0f;
      ((float4*)srow)[lane] = vs;
    } else if (lane == 16){
      if (hard >= 64) srow[hard] = 1.0f;
    } else if (lane == 17){
      orow[codei] = 1.0f;
    } else if (lane == 18){
      code_out[row] = (float)codei;
    }
  }
}

extern "C" void kernel_launch(void* const* d_in, const int* in_sizes, int n_in,
                              void* d_out, int out_size, void* d_ws, size_t ws_size,
                              hipStream_t stream) {
  const float* x    = (const float*)d_in[0];
  const float* cb   = (const float*)d_in[1];
  const float* temp = (const float*)d_in[2];
  float* out    = (float*)d_out;
  float* sample = out;                       // 33554432
  float* code   = out + 33554432;            // 8192
  float* onehot = code + 8192;               // 33554432
  float* logit  = onehot + 33554432;         // 33554432
  float* ws     = (float*)d_ws;

  const bool use_ws = ws_size >= (size_t)8192 * 64 * sizeof(float);
  if (use_ws){
    hipLaunchKernelGGL((k_logits<true>), dim3(4096), dim3(512), 0, stream,
                       x, cb, temp, logit, sample, onehot, ws);
    hipLaunchKernelGGL((k_finalize<true>), dim3(2048), dim3(256), 0, stream,
                       sample, code, onehot, ws);
  } else {
    hipLaunchKernelGGL((k_logits<false>), dim3(4096), dim3(512), 0, stream,
                       x, cb, temp, logit, sample, onehot, ws);
    hipLaunchKernelGGL((k_finalize<false>), dim3(2048), dim3(256), 0, stream,
                       sample, code, onehot, ws);
  }
}

// Round 19
// 122.994 us; speedup vs baseline: 9.8079x; 1.0234x over previous
//
#include <hip/hip_runtime.h>
#include <stdint.h>

// x: (8,128,16,16) f32 ; codebook: (4,4096,32) f32 ; temperature: (4,1,1,1)
// row = (n*4+m)*256 + hw, 8192 rows, K=4096, D=32
// outputs (flat f32): sample[33554432] code[8192] one_hot[33554432] logit[33554432]
//
// ROUND 19 = R18 (125.9us) + ONE change: the block's zero-fill moves from the
// post-barrier kernel tail into the gumbel t-loop (2 float4/thread/iter).
// R15's interleave failed because of the __launch_bounds__(512,8) VGPR cap
// (spill to scratch); no cap here. R7's barrier-drain only bites on BURST
// stores before a barrier — spread at 2x16B per ~1500 VALU cycles, the
// residual queue at the reduction barrier is ~32B/lane (one latency).

typedef short bf16x8 __attribute__((ext_vector_type(8)));
typedef float f32x4  __attribute__((ext_vector_type(4)));

__device__ __forceinline__ uint32_t rotl32(uint32_t x, uint32_t r){
  return (x << r) | (x >> (32u - r));
}

// JAX threefry2x32, key (0,42), partitionable scheme. Bits VALIDATED bit-exact
// (R2,4,6..); fast-log path VALIDATED (R11,R12,R13,R17,R18).
__device__ __forceinline__ float gumbel_from_e(uint32_t e){
  uint32_t x0 = 0u, x1 = e;
  const uint32_t ks0 = 0u, ks1 = 42u, ks2 = 0x1BD11BF0u;
  x0 += ks0; x1 += ks1;
#define TFR4(a,b,c,d2) \
  x0 += x1; x1 = rotl32(x1,(a)); x1 ^= x0; \
  x0 += x1; x1 = rotl32(x1,(b)); x1 ^= x0; \
  x0 += x1; x1 = rotl32(x1,(c)); x1 ^= x0; \
  x0 += x1; x1 = rotl32(x1,(d2)); x1 ^= x0;
  TFR4(13,15,26,6)  x0 += ks1; x1 += ks2 + 1u;
  TFR4(17,29,16,24) x0 += ks2; x1 += ks0 + 2u;
  TFR4(13,15,26,6)  x0 += ks0; x1 += ks1 + 3u;
  TFR4(17,29,16,24) x0 += ks1; x1 += ks2 + 4u;
  TFR4(13,15,26,6)  x0 += ks2; x1 += ks0 + 5u;
#undef TFR4
  uint32_t bits = x0 ^ x1;
  float u = __uint_as_float((bits >> 9) | 0x3F800000u) - 1.0f;
  u = fminf(fmaxf(u, 1.1920929e-07f), __uint_as_float(0x3F7FFFFEu));
  const float LN2 = 0.69314718055994531f;
  float v = -LN2 * __log2f(u);
  return -LN2 * __log2f(v);
}

// Truncating bf16 split: v ~= hi + lo, |v-(hi+lo)| <= 2^-16 |v|.
__device__ __forceinline__ void split_bf16(float v, unsigned short& hi, unsigned short& lo){
  uint32_t b = __float_as_uint(v);
  hi = (unsigned short)(b >> 16);
  float r = v - __uint_as_float(b & 0xFFFF0000u);
  lo = (unsigned short)(__float_as_uint(r) >> 16);
}

// Kernel 1: grid 4096 = m(4) x rowtile(64) x ktile(16); block 512 thr (8 waves),
// 32 rows x 256 k. bf16x3 MFMA GEMM (R17-validated layouts), ws partials
// (R18-validated), zero-fill interleaved into the t-loop.
template<bool USE_WS>
__global__ __launch_bounds__(512) void k_logits(
    const float* __restrict__ x, const float* __restrict__ cb,
    const float* __restrict__ temp, float* __restrict__ logit_out,
    float* __restrict__ sample, float* __restrict__ onehot,
    float* __restrict__ part_ws){
  __shared__ __align__(16) unsigned short cbuf[20480]; // hi/lo planes: 256 x 40 each
  __shared__ __align__(16) unsigned short xbuf[2560];  // hi/lo planes: 32 x 40 each
  __shared__ float c2l[256];
  __shared__ float x2l[32];

  const int tid = threadIdx.x;
  const int b = blockIdx.x;
  const int kt = b & 15;
  const int rt = (b >> 4) & 63;
  const int m  = b >> 10;
  const int n  = rt >> 3;
  const int hw0 = (rt & 7) << 5;
  const int k0 = kt << 8;
  const int rowbase = ((n << 2) + m) * 256 + hw0;

  // ---- stage x tile (32 rows x 32 d) as bf16 hi/lo planes ----
  const float* xm = x + ((n * 128 + m * 32) * 256 + hw0);
  #pragma unroll
  for (int i = 0; i < 2; ++i){
    int idx = tid + (i << 9);
    int d = idx >> 5, r = idx & 31;
    float v = xm[(d << 8) + r];
    unsigned short h, l;
    split_bf16(v, h, l);
    xbuf[r * 40 + d] = h;
    xbuf[1280 + r * 40 + d] = l;
  }
  // ---- stage codebook tile: bf16 hi/lo + shuffle-tree c2 ----
  const float4* cb4 = (const float4*)(cb + (m * 131072 + k0 * 32));
  #pragma unroll
  for (int i = 0; i < 4; ++i){
    int f = tid + (i << 9);
    float4 v = cb4[f];
    int kk = f >> 3, dq = f & 7;
    unsigned short h0,h1,h2,h3,l0,l1,l2,l3;
    split_bf16(v.x, h0, l0); split_bf16(v.y, h1, l1);
    split_bf16(v.z, h2, l2); split_bf16(v.w, h3, l3);
    uint2 hw_, lw_;
    hw_.x = (uint32_t)h0 | ((uint32_t)h1 << 16);
    hw_.y = (uint32_t)h2 | ((uint32_t)h3 << 16);
    lw_.x = (uint32_t)l0 | ((uint32_t)l1 << 16);
    lw_.y = (uint32_t)l2 | ((uint32_t)l3 << 16);
    *(uint2*)&cbuf[kk * 40 + (dq << 2)] = hw_;
    *(uint2*)&cbuf[10240 + kk * 40 + (dq << 2)] = lw_;
    float p = fmaf(v.x, v.x, fmaf(v.y, v.y, fmaf(v.z, v.z, v.w * v.w)));
    p += __shfl_xor(p, 1);
    p += __shfl_xor(p, 2);
    p += __shfl_xor(p, 4);
    if (dq == 0) c2l[kk] = p;
  }
  __syncthreads();

  // ---- x2 from recombined planes (consistent with MFMA's x-tilde) ----
  if (tid < 32){
    float s = 0.f;
    #pragma unroll
    for (int d = 0; d < 32; ++d){
      float vh = __uint_as_float(((uint32_t)xbuf[tid * 40 + d]) << 16);
      float vl = __uint_as_float(((uint32_t)xbuf[1280 + tid * 40 + d]) << 16);
      float v = vh + vl;
      s = fmaf(v, v, s);
    }
    x2l[tid] = s;
  }
  __syncthreads();

  const int lane = tid & 63;
  const int w    = tid >> 6;
  const int mh   = w >> 2;
  const int ng   = w & 3;
  const int l15  = lane & 15;
  const int kgrp = lane >> 4;

  bf16x8 Ah = *(const bf16x8*)&xbuf[(mh * 16 + l15) * 40 + (kgrp << 3)];
  bf16x8 Al = *(const bf16x8*)&xbuf[1280 + (mh * 16 + l15) * 40 + (kgrp << 3)];

  float x2r[4];
  #pragma unroll
  for (int j = 0; j < 4; ++j) x2r[j] = x2l[mh * 16 + (kgrp << 2) + j];

  const float tcl = fmaxf(temp[m], 1e-6f);
  const float4 z4 = make_float4(0.f, 0.f, 0.f, 0.f);
  float bl[4], bg[4]; int bli[4], bgi[4];
  #pragma unroll
  for (int j = 0; j < 4; ++j){ bl[j] = -INFINITY; bg[j] = -INFINITY; bli[j] = 0; bgi[j] = 0; }

  #pragma unroll
  for (int t = 0; t < 4; ++t){
    const int nt = (ng << 2) + t;
    const int k_blk = (nt << 4) + l15;
    bf16x8 Bh = *(const bf16x8*)&cbuf[k_blk * 40 + (kgrp << 3)];
    bf16x8 Bl = *(const bf16x8*)&cbuf[10240 + k_blk * 40 + (kgrp << 3)];
    f32x4 acc = {0.f, 0.f, 0.f, 0.f};
    acc = __builtin_amdgcn_mfma_f32_16x16x32_bf16(Ah, Bh, acc, 0, 0, 0);
    acc = __builtin_amdgcn_mfma_f32_16x16x32_bf16(Ah, Bl, acc, 0, 0, 0);
    acc = __builtin_amdgcn_mfma_f32_16x16x32_bf16(Al, Bh, acc, 0, 0, 0);

    const float c2 = c2l[k_blk];
    const int k_g = k0 + k_blk;
    #pragma unroll
    for (int j = 0; j < 4; ++j){
      const int r_blk = mh * 16 + (kgrp << 2) + j;   // D: col=lane&15, row=(lane>>4)*4+reg
      const int row_g = rowbase + r_blk;
      float dist = x2r[j] + c2 - 2.0f * acc[j];
      float lgt = (-dist) * 0.015625f * tcl;
      logit_out[((size_t)row_g << 12) + k_g] = lgt;
      float lg = lgt + gumbel_from_e(((uint32_t)row_g << 12) + (uint32_t)k_g);
      if (lgt > bl[j]) { bl[j] = lgt; bli[j] = k_g; }
      if (lg  > bg[j]) { bg[j] = lg;  bgi[j] = k_g; }
    }

    if (USE_WS){
      // interleaved zero-fill slice t (paced by the 16 gumbels above; residual
      // in-flight at the reduction barrier is ~32B/lane — R7-safe)
      int s = tid + (t << 9);
      int r2 = s >> 6, w4 = s & 63;
      size_t f4 = (((size_t)(rowbase + r2)) << 10) + (k0 >> 2) + w4;
      ((float4*)onehot)[f4] = z4;
      ((float4*)sample)[f4] = z4;
    }
  }

  // ---- two-stage LDS argmax reduction (scratch overlays cbuf) ----
  __syncthreads();
  float* red = (float*)cbuf;
  #pragma unroll
  for (int j = 0; j < 4; ++j){
    int row = mh * 16 + (kgrp << 2) + j;
    int slot = (ng << 4) + l15;
    red[        row * 65 + slot] = bl[j];
    red[2080 +  row * 65 + slot] = __int_as_float(bli[j]);
    red[4160 +  row * 65 + slot] = bg[j];
    red[6240 +  row * 65 + slot] = __int_as_float(bgi[j]);
  }
  __syncthreads();
  if (tid < 64){
    const int r = tid & 31;
    const bool doG = (tid >= 32);
    const int off_v = doG ? 4160 : 0;
    const int off_i = doG ? 6240 : 2080;
    float bv = -INFINITY; int bi = 0;
    for (int g2 = 0; g2 < 64; ++g2){
      float v = red[off_v + r * 65 + g2];
      int  ix = __float_as_int(red[off_i + r * 65 + g2]);
      if (v > bv || (v == bv && ix < bi)){ bv = v; bi = ix; }
    }
    const int row_g = rowbase + r;
    if (USE_WS){
      *(float2*)&part_ws[((size_t)row_g << 6) + (kt << 2) + (doG ? 2 : 0)]
          = make_float2(bv, __int_as_float(bi));
    } else {
      float* part = sample + ((size_t)row_g << 12);
      part[(doG ? 32 : 0)  + kt] = bv;
      part[(doG ? 48 : 16) + kt] = __int_as_float(bi);
    }
  }

  if (!USE_WS){
    // fallback: R18-validated tail fill
    #pragma unroll
    for (int i2 = 0; i2 < 4; ++i2){
      int s = tid + (i2 << 9);
      int r = s >> 6, w4 = s & 63;
      size_t f4 = (((size_t)(rowbase + r)) << 10) + (k0 >> 2) + w4;
      ((float4*)onehot)[f4] = z4;
      if (!(kt == 0 && w4 < 16))
        ((float4*)sample)[f4] = z4;
    }
  }
}

// Kernel 2: one wave per row (2048 blocks x 256). Reduce 16 partials, scatter.
template<bool USE_WS>
__global__ __launch_bounds__(256) void k_finalize(
    float* __restrict__ sample, float* __restrict__ code_out,
    float* __restrict__ onehot, const float* __restrict__ part_ws){
  const int tid = threadIdx.x;
  const int row = (blockIdx.x << 2) + (tid >> 6);
  const int lane = tid & 63;
  float* srow = sample + ((size_t)row << 12);
  float* orow = onehot + ((size_t)row << 12);

  const int g = (lane >> 4) & 1;
  const int l16 = lane & 15;
  float v; int ix;
  if (lane < 32){
    if (USE_WS){
      float2 p2 = *(const float2*)&part_ws[((size_t)row << 6) + (l16 << 2) + (g ? 2 : 0)];
      v = p2.x; ix = __float_as_int(p2.y);
    } else {
      v  = srow[g * 32 + l16];
      ix = __float_as_int(srow[g * 32 + 16 + l16]);
    }
  } else { v = -INFINITY; ix = 0x7fffffff; }
  #pragma unroll
  for (int off = 1; off < 16; off <<= 1){
    float ov = __shfl_xor(v, off, 16);
    int   oi = __shfl_xor(ix, off, 16);
    if (ov > v || (ov == v && oi < ix)){ v = ov; ix = oi; }
  }
  const int codei = __shfl(ix, 0, 64);   // L winner
  const int hard  = __shfl(ix, 16, 64);  // G winner

  if (USE_WS){
    if (lane == 0)      srow[hard]  = 1.0f;
    else if (lane == 1) orow[codei] = 1.0f;
    else if (lane == 2) code_out[row] = (float)codei;
  } else {
    if (lane < 16){
      float4 vs = make_float4(0.f, 0.f, 0.f, 0.f);
      if ((hard >> 2) == lane) ((float*)&vs)[hard & 3] = 1.0f;
      ((float4*)srow)[lane] = vs;
    } else if (lane == 16){
      if (hard >= 64) srow[hard] = 1.0f;
    } else if (lane == 17){
      orow[codei] = 1.0f;
    } else if (lane == 18){
      code_out[row] = (float)codei;
    }
  }
}

extern "C" void kernel_launch(void* const* d_in, const int* in_sizes, int n_in,
                              void* d_out, int out_size, void* d_ws, size_t ws_size,
                              hipStream_t stream) {
  const float* x    = (const float*)d_in[0];
  const float* cb   = (const float*)d_in[1];
  const float* temp = (const float*)d_in[2];
  float* out    = (float*)d_out;
  float* sample = out;                       // 33554432
  float* code   = out + 33554432;            // 8192
  float* onehot = code + 8192;               // 33554432
  float* logit  = onehot + 33554432;         // 33554432
  float* ws     = (float*)d_ws;

  const bool use_ws = ws_size >= (size_t)8192 * 64 * sizeof(float);
  if (use_ws){
    hipLaunchKernelGGL((k_logits<true>), dim3(4096), dim3(512), 0, stream,
                       x, cb, temp, logit, sample, onehot, ws);
    hipLaunchKernelGGL((k_finalize<true>), dim3(2048), dim3(256), 0, stream,
                       sample, code, onehot, ws);
  } else {
    hipLaunchKernelGGL((k_logits<false>), dim3(4096), dim3(512), 0, stream,
                       x, cb, temp, logit, sample, onehot, ws);
    hipLaunchKernelGGL((k_finalize<false>), dim3(2048), dim3(256), 0, stream,
                       sample, code, onehot, ws);
  }
}